// Round 1
// baseline (558.633 us; speedup 1.0000x reference)
//
#include <hip/hip_runtime.h>
#include <hip/hip_cooperative_groups.h>
#include <cmath>

namespace cg = cooperative_groups;

#define T_LEN 60000
#define BATCH 4
#define NBANDS 8
#define FB 32
#define EPS 1e-8f

#define K1_TILE 496
#define K1_ROWLEN 512   // staged floats per row: window [tile0-8, tile0+504)
#define K1_NBX ((T_LEN + K1_TILE - 1) / K1_TILE)   // 121

// ---------------- K1: x -> xp. grid (121, 8, 4), block 256.  (UNCHANGED —
// at HBM roofline: 254 MB mandatory read, 16 float4 loads in flight/thread)
__global__ __launch_bounds__(256) void k1_xp(
        const float* __restrict__ x, const float* __restrict__ log_gamma,
        const float* __restrict__ diff_w, const float* __restrict__ diff_b,
        float* __restrict__ xp, int* __restrict__ mslots) {
    extern __shared__ float sh[];   // 32 * 512 floats = 64 KB
    const int tid = threadIdx.x;
    const int bx = blockIdx.x, band = blockIdx.y, b = blockIdx.z;
    if (bx == 0 && band == 0 && b == 0 && tid < 8)
        mslots[tid] = 0;  // zero m1[4], m2[4] (ws poisoned 0xAA)
    const int tile0 = bx * K1_TILE;
    const int w0 = tile0 - 8;  // global t of sh[r][0]
    const float* base = x + ((size_t)((b * NBANDS + band) * FB)) * T_LEN;
    const bool interior = (w0 >= 0) && (w0 + K1_ROWLEN <= T_LEN);
    if (interior) {
#pragma unroll
        for (int c = 0; c < 16; ++c) {
            const int idx = c * 1024 + tid * 4;   // float index into sh
            const int r = idx >> 9;               // row 0..31
            const int i = idx & 511;
            float4 v = *(const float4*)(base + (size_t)r * T_LEN + w0 + i);
            *(float4*)&sh[idx] = v;
        }
    } else {  // bx==0 or last: predicated scalar staging
        for (int c = 0; c < 16; ++c) {
            const int idx = c * 1024 + tid * 4;
            const int r = idx >> 9;
            const int i = idx & 511;
            const float* rowp = base + (size_t)r * T_LEN;
#pragma unroll
            for (int j = 0; j < 4; ++j) {
                const int t = w0 + i + j;
                sh[idx + j] = (t >= 0 && t < T_LEN) ? rowp[t] : 0.f;
            }
        }
    }
    __syncthreads();
    const float gamma = __expf(log_gamma[band]);
    float dw[5];
#pragma unroll
    for (int k = 0; k < 5; ++k) dw[k] = diff_w[band * 5 + k];
    const float db = diff_b[band];
    const int t0 = tile0 + 2 * tid;
    if (tid < 248 && t0 < T_LEN) {
        float acc0 = 0.f, acc1 = 0.f;
        const int i0 = 2 * tid + 6;  // sh row-index of t0-2 (8B-aligned)
#pragma unroll 4
        for (int r = 0; r < FB; ++r) {
            const float* rp = &sh[r * K1_ROWLEN];
            float2 pa = *(const float2*)(rp + i0);
            float2 pb = *(const float2*)(rp + i0 + 2);
            float2 pc = *(const float2*)(rp + i0 + 4);
            float e0 = __logf(fmaf(gamma, pa.x, 1.f));
            float e1 = __logf(fmaf(gamma, pa.y, 1.f));
            float e2 = __logf(fmaf(gamma, pb.x, 1.f));
            float e3 = __logf(fmaf(gamma, pb.y, 1.f));
            float e4 = __logf(fmaf(gamma, pc.x, 1.f));
            float e5 = __logf(fmaf(gamma, pc.y, 1.f));
            float xd0 = db, xd1 = db;
            xd0 = fmaf(dw[0], e0, xd0); xd1 = fmaf(dw[0], e1, xd1);
            xd0 = fmaf(dw[1], e1, xd0); xd1 = fmaf(dw[1], e2, xd1);
            xd0 = fmaf(dw[2], e2, xd0); xd1 = fmaf(dw[2], e3, xd1);
            xd0 = fmaf(dw[3], e3, xd0); xd1 = fmaf(dw[3], e4, xd1);
            xd0 = fmaf(dw[4], e4, xd0); xd1 = fmaf(dw[4], e5, xd1);
            acc0 += fmaxf(xd0, 0.f);
            acc1 += fmaxf(xd1, 0.f);
        }
        float* op = xp + ((size_t)(b * NBANDS + band)) * T_LEN + t0;
        op[0] = acc0;
        if (t0 + 1 < T_LEN) op[1] = acc1;
    }
}

// ---------------- K23: fused K2+K3a+K3b as ONE cooperative kernel.
// Phase A: xp -> xg (composite 25-tap), block-max -> atomicMax m1.
//   xg for this block's 256 t's also parked in LDS (xgs) + sig path later.
// grid.sync()
// Phase B: fm staged from LDS xgs (+14-value global halo), 15-tap fg conv,
//   sigmoid kept IN REGISTERS, sf_out written, block-max -> atomicMax m2.
// grid.sync()
// Phase C: fn_out = sig * 1/(m2+eps) straight from registers.
#define K2_STAGE 288  // [T0-16, T0+272)
__global__ __launch_bounds__(256) void k23_fused(
        const float* __restrict__ xp,
        const float* __restrict__ la_w, const float* __restrict__ la_b,
        const float* __restrict__ mix_w, const float* __restrict__ g_w,
        const float* __restrict__ g_b,
        float* __restrict__ xg, int* __restrict__ m1_bits,
        const float* __restrict__ fc_w, const float* __restrict__ fc_b,
        const float* __restrict__ fg_w, const float* __restrict__ fg_b,
        float* __restrict__ sf_out, float* __restrict__ fn_out,
        int* __restrict__ m2_bits) {
    __shared__ float sh[NBANDS][K2_STAGE];   // 9216 B
    __shared__ float H[NBANDS][25];          //  800 B
    __shared__ float red[4];
    __shared__ float xgs[256];               // this block's xg values
    __shared__ float shfm[272];              // fm stage for phase B
    const int tid = threadIdx.x;
    const int T0 = blockIdx.x * 256;
    const int b = blockIdx.y;
    const float* xpb = xp + (size_t)b * NBANDS * T_LEN;

    // ---- Phase A: composite 25-tap xp -> xg (identical math to old K2)
    for (int idx = tid; idx < NBANDS * (K2_STAGE / 4); idx += 256) {
        int c = idx / (K2_STAGE / 4);
        int i4 = idx % (K2_STAGE / 4);
        int g = T0 - 16 + 4 * i4;
        const float* rowp = xpb + (size_t)c * T_LEN;
        float4 v;
        if (g >= 0 && g + 3 < T_LEN) {
            v = *(const float4*)(rowp + g);
        } else {
            v.x = (g + 0 >= 0 && g + 0 < T_LEN) ? rowp[g + 0] : 0.f;
            v.y = (g + 1 >= 0 && g + 1 < T_LEN) ? rowp[g + 1] : 0.f;
            v.z = (g + 2 >= 0 && g + 2 < T_LEN) ? rowp[g + 2] : 0.f;
            v.w = (g + 3 >= 0 && g + 3 < T_LEN) ? rowp[g + 3] : 0.f;
        }
        *(float4*)&sh[c][4 * i4] = v;
    }
    if (tid < 200) {
        int c = tid / 25, m = tid % 25;
        int klo = m - 14 > 0 ? m - 14 : 0;
        int khi = m < 10 ? m : 10;
        float mw = mix_w[c], s = 0.f;
        for (int k = klo; k <= khi; ++k)
            s += g_w[m - k] * (mw * ((k == 5 ? 1.f : 0.f) - la_w[c * 11 + k]));
        H[c][m] = s;
    }
    float Sg = 0.f;
#pragma unroll
    for (int j = 0; j < 15; ++j) Sg += g_w[j];
    float C0 = 0.f;
#pragma unroll
    for (int c = 0; c < NBANDS; ++c) C0 -= mix_w[c] * la_b[c];
    const float cst = g_b[0] + Sg * C0;
    __syncthreads();
    const int t = T0 + tid;
    float v = cst;
#pragma unroll 1
    for (int c = 0; c < NBANDS; ++c) {
        float a = 0.f;
#pragma unroll
        for (int m = 0; m < 25; ++m) a = fmaf(H[c][m], sh[c][tid + 4 + m], a);
        v += a;
    }
    if (t < 7 || (t >= T_LEN - 7 && t < T_LEN)) {
        v = g_b[0];
        for (int jj = 0; jj < 15; ++jj) {
            int tp = t + jj - 7;
            if (tp < 0 || tp >= T_LEN) continue;
            float xm = C0;
            for (int c = 0; c < NBANDS; ++c) {
                float mw = mix_w[c];
                for (int k = 0; k < 11; ++k) {
                    int i = tp + k + 11 - T0;
                    xm = fmaf(mw * ((k == 5 ? 1.f : 0.f) - la_w[c * 11 + k]),
                              sh[c][i], xm);
                }
            }
            v = fmaf(g_w[jj], xm, v);
        }
    }
    float vmax = 0.f;
    if (t < T_LEN) {
        v = fmaxf(v, 0.f);
        xg[(size_t)b * T_LEN + t] = v;
        vmax = v;
        xgs[tid] = v;
    } else {
        xgs[tid] = 0.f;
    }
#pragma unroll
    for (int off = 32; off > 0; off >>= 1) vmax = fmaxf(vmax, __shfl_down(vmax, off));
    if ((tid & 63) == 0) red[tid >> 6] = vmax;
    __syncthreads();
    if (tid == 0) {
        float m = fmaxf(fmaxf(red[0], red[1]), fmaxf(red[2], red[3]));
        atomicMax(&m1_bits[b], __float_as_int(m));
    }

    // ---- grid-wide: m1 complete, xg globally visible
    cg::this_grid().sync();

    // ---- Phase B: sf_out + sigmoid(fs) in registers + m2
    const float inv = 1.f / (__int_as_float(m1_bits[b]) + EPS);
    const float sfc = fc_w[0] + fc_w[1] + fc_w[2] + fc_w[3];
    const float fcb = fc_b[0];
    for (int i = tid; i < 270; i += 256) {
        int tt = T0 + i - 7;
        float fmv = 0.f;
        if (tt >= 0 && tt < T_LEN) {
            float xv = (tt >= T0 && tt < T0 + 256)
                           ? xgs[tt - T0]
                           : xg[(size_t)b * T_LEN + tt];   // 14-value halo
            fmv = fmaf(sfc, xv * inv, fcb);
        }
        shfm[i] = fmv;
    }
    __syncthreads();
    float fs = fg_b[0];
#pragma unroll
    for (int k = 0; k < 15; ++k) fs = fmaf(fg_w[k], shfm[tid + k], fs);
    float sig = 1.f / (1.f + __expf(-fs));
    float v2;
    if (t < T_LEN) {
        sf_out[(size_t)b * T_LEN + t] = xgs[tid] * inv;
        v2 = sig;
    } else {
        v2 = 0.f;
    }
#pragma unroll
    for (int off = 32; off > 0; off >>= 1) v2 = fmaxf(v2, __shfl_down(v2, off));
    if ((tid & 63) == 0) red[tid >> 6] = v2;
    __syncthreads();
    if (tid == 0) {
        float m = fmaxf(fmaxf(red[0], red[1]), fmaxf(red[2], red[3]));
        atomicMax(&m2_bits[b], __float_as_int(m));
    }

    // ---- grid-wide: m2 complete
    cg::this_grid().sync();

    // ---- Phase C: normalize from registers (no fa round-trip)
    if (t < T_LEN) {
        const float inv2 = 1.f / (__int_as_float(m2_bits[b]) + EPS);
        fn_out[(size_t)b * T_LEN + t] = sig * inv2;
    }
}

extern "C" void kernel_launch(void* const* d_in, const int* in_sizes, int n_in,
                              void* d_out, int out_size, void* d_ws, size_t ws_size,
                              hipStream_t stream) {
    const float* x    = (const float*)d_in[0];
    const float* lg   = (const float*)d_in[1];
    const float* dw   = (const float*)d_in[2];
    const float* db   = (const float*)d_in[3];
    const float* law  = (const float*)d_in[4];
    const float* lab  = (const float*)d_in[5];
    const float* mixw = (const float*)d_in[6];
    const float* gw   = (const float*)d_in[7];
    const float* gb   = (const float*)d_in[8];
    const float* fcw  = (const float*)d_in[9];
    const float* fcb  = (const float*)d_in[10];
    const float* fgw  = (const float*)d_in[11];
    const float* fgb  = (const float*)d_in[12];

    float* ws = (float*)d_ws;
    float* xp = ws;                                   // 4*8*60000 floats
    float* xg = ws + (size_t)BATCH * NBANDS * T_LEN;  // 240,000 floats
    int*   m1 = (int*)(xg + (size_t)BATCH * T_LEN);   // m1[4] then m2[4]
    int*   m2 = m1 + 4;

    float* sf_out = (float*)d_out;
    float* fn_out = sf_out + (size_t)BATCH * T_LEN;

    const int tb256 = (T_LEN + 255) / 256;            // 235

    k1_xp<<<dim3(K1_NBX, NBANDS, BATCH), dim3(256),
            FB * K1_ROWLEN * sizeof(float), stream>>>(
        x, lg, dw, db, xp, m1);

    void* args[] = {
        (void*)&xp, (void*)&law, (void*)&lab, (void*)&mixw, (void*)&gw,
        (void*)&gb, (void*)&xg, (void*)&m1, (void*)&fcw, (void*)&fcb,
        (void*)&fgw, (void*)&fgb, (void*)&sf_out, (void*)&fn_out, (void*)&m2
    };
    hipLaunchCooperativeKernel((void*)k23_fused, dim3(tb256, BATCH), dim3(256),
                               args, 0, stream);
}

// Round 2
// 423.719 us; speedup vs baseline: 1.3184x; 1.3184x over previous
//
#include <hip/hip_runtime.h>
#include <cmath>

#define T_LEN 60000
#define BATCH 4
#define NBANDS 8
#define FB 32
#define EPS 1e-8f

// ---------------- K1: x -> xp. LDS-free. 1 thread = 4 outputs (t0..t0+3),
// window [t0-2, t0+6) read straight from global via 4x float2; adjacent
// lanes' overlapping reads hit L1 (contiguous lines), so HBM fetch stays 1x.
// No barrier, no LDS -> ~8 blocks/CU resident, loads pipeline across the
// 32-row loop. Math identical to staged version (same __logf(fmaf) values,
// same row accumulation order); OOB window elems use raw 0 (log1p(g*0)=0
// reproduces the reference's zero-padded xl).
#define K1_TPB 256
#define K1_SPAN (K1_TPB * 4)   // 1024 t per block
#define K1_NBX ((T_LEN + K1_SPAN - 1) / K1_SPAN)   // 59

__global__ __launch_bounds__(256) void k1_xp(
        const float* __restrict__ x, const float* __restrict__ log_gamma,
        const float* __restrict__ diff_w, const float* __restrict__ diff_b,
        float* __restrict__ xp, int* __restrict__ mslots) {
    const int tid = threadIdx.x;
    const int bx = blockIdx.x, band = blockIdx.y, b = blockIdx.z;
    if (bx == 0 && band == 0 && b == 0 && tid < 8)
        mslots[tid] = 0;  // zero m1[4], m2[4] (ws poisoned 0xAA)
    const int t0 = bx * K1_SPAN + tid * 4;
    if (t0 >= T_LEN) return;
    const float gamma = __expf(log_gamma[band]);
    float dw[5];
#pragma unroll
    for (int k = 0; k < 5; ++k) dw[k] = diff_w[band * 5 + k];
    const float db = diff_b[band];
    const float* base = x + ((size_t)((b * NBANDS + band) * FB)) * T_LEN;
    float acc0 = 0.f, acc1 = 0.f, acc2 = 0.f, acc3 = 0.f;
    const bool interior = (t0 >= 2) && (t0 + 6 <= T_LEN);
    if (interior) {
        const float* rp = base + t0;
#pragma unroll 4
        for (int r = 0; r < FB; ++r, rp += T_LEN) {
            float2 va = *(const float2*)(rp - 2);   // t0-2, t0-1   (8B aligned)
            float2 vb = *(const float2*)(rp);       // t0,   t0+1
            float2 vc = *(const float2*)(rp + 2);   // t0+2, t0+3
            float2 vd = *(const float2*)(rp + 4);   // t0+4, t0+5
            float e0 = __logf(fmaf(gamma, va.x, 1.f));
            float e1 = __logf(fmaf(gamma, va.y, 1.f));
            float e2 = __logf(fmaf(gamma, vb.x, 1.f));
            float e3 = __logf(fmaf(gamma, vb.y, 1.f));
            float e4 = __logf(fmaf(gamma, vc.x, 1.f));
            float e5 = __logf(fmaf(gamma, vc.y, 1.f));
            float e6 = __logf(fmaf(gamma, vd.x, 1.f));
            float e7 = __logf(fmaf(gamma, vd.y, 1.f));
            float x0 = db, x1 = db, x2 = db, x3 = db;
            x0 = fmaf(dw[0], e0, x0); x1 = fmaf(dw[0], e1, x1);
            x2 = fmaf(dw[0], e2, x2); x3 = fmaf(dw[0], e3, x3);
            x0 = fmaf(dw[1], e1, x0); x1 = fmaf(dw[1], e2, x1);
            x2 = fmaf(dw[1], e3, x2); x3 = fmaf(dw[1], e4, x3);
            x0 = fmaf(dw[2], e2, x0); x1 = fmaf(dw[2], e3, x1);
            x2 = fmaf(dw[2], e4, x2); x3 = fmaf(dw[2], e5, x3);
            x0 = fmaf(dw[3], e3, x0); x1 = fmaf(dw[3], e4, x1);
            x2 = fmaf(dw[3], e5, x2); x3 = fmaf(dw[3], e6, x3);
            x0 = fmaf(dw[4], e4, x0); x1 = fmaf(dw[4], e5, x1);
            x2 = fmaf(dw[4], e6, x2); x3 = fmaf(dw[4], e7, x3);
            acc0 += fmaxf(x0, 0.f);
            acc1 += fmaxf(x1, 0.f);
            acc2 += fmaxf(x2, 0.f);
            acc3 += fmaxf(x3, 0.f);
        }
    } else {  // first/last thread of the t-range: bounds-checked scalar path
        float acc[4] = {0.f, 0.f, 0.f, 0.f};
        for (int r = 0; r < FB; ++r) {
            const float* rowp = base + (size_t)r * T_LEN;
            float e[8];
#pragma unroll
            for (int j = 0; j < 8; ++j) {
                int t = t0 + j - 2;
                float xv = (t >= 0 && t < T_LEN) ? rowp[t] : 0.f;
                e[j] = __logf(fmaf(gamma, xv, 1.f));
            }
#pragma unroll
            for (int j = 0; j < 4; ++j) {
                float xd = db;
                xd = fmaf(dw[0], e[j + 0], xd);
                xd = fmaf(dw[1], e[j + 1], xd);
                xd = fmaf(dw[2], e[j + 2], xd);
                xd = fmaf(dw[3], e[j + 3], xd);
                xd = fmaf(dw[4], e[j + 4], xd);
                acc[j] += fmaxf(xd, 0.f);
            }
        }
        acc0 = acc[0]; acc1 = acc[1]; acc2 = acc[2]; acc3 = acc[3];
    }
    // T_LEN % 4 == 0 and t0 % 4 == 0, so t0 < T_LEN implies t0+3 < T_LEN.
    float4 o; o.x = acc0; o.y = acc1; o.z = acc2; o.w = acc3;
    *(float4*)(xp + ((size_t)(b * NBANDS + band)) * T_LEN + t0) = o;
}

// ---------------- K2: xp -> xg via composite 25-tap kernel (la-subtract + band
// mix + gaussian fused; all linear). Tile 256, 1 output/thread, stride-1 LDS.
// Boundary t (<7 or >=T-7) recomputed two-stage FROM LDS (no global loads).
#define K2_STAGE 288  // [T0-16, T0+272)
__global__ __launch_bounds__(256) void k2_xg(
        const float* __restrict__ xp,
        const float* __restrict__ la_w, const float* __restrict__ la_b,
        const float* __restrict__ mix_w, const float* __restrict__ g_w,
        const float* __restrict__ g_b,
        float* __restrict__ xg, int* __restrict__ m1_bits) {
    __shared__ float sh[NBANDS][K2_STAGE];
    __shared__ float H[NBANDS][25];
    __shared__ float red[4];
    const int tid = threadIdx.x;
    const int T0 = blockIdx.x * 256;
    const int b = blockIdx.y;
    const float* xpb = xp + (size_t)b * NBANDS * T_LEN;
    for (int idx = tid; idx < NBANDS * (K2_STAGE / 4); idx += 256) {
        int c = idx / (K2_STAGE / 4);
        int i4 = idx % (K2_STAGE / 4);
        int g = T0 - 16 + 4 * i4;
        const float* rowp = xpb + (size_t)c * T_LEN;
        float4 v;
        if (g >= 0 && g + 3 < T_LEN) {
            v = *(const float4*)(rowp + g);
        } else {
            v.x = (g + 0 >= 0 && g + 0 < T_LEN) ? rowp[g + 0] : 0.f;
            v.y = (g + 1 >= 0 && g + 1 < T_LEN) ? rowp[g + 1] : 0.f;
            v.z = (g + 2 >= 0 && g + 2 < T_LEN) ? rowp[g + 2] : 0.f;
            v.w = (g + 3 >= 0 && g + 3 < T_LEN) ? rowp[g + 3] : 0.f;
        }
        *(float4*)&sh[c][4 * i4] = v;
    }
    if (tid < 200) {
        int c = tid / 25, m = tid % 25;
        int klo = m - 14 > 0 ? m - 14 : 0;
        int khi = m < 10 ? m : 10;
        float mw = mix_w[c], s = 0.f;
        for (int k = klo; k <= khi; ++k)
            s += g_w[m - k] * (mw * ((k == 5 ? 1.f : 0.f) - la_w[c * 11 + k]));
        H[c][m] = s;
    }
    float Sg = 0.f;
#pragma unroll
    for (int j = 0; j < 15; ++j) Sg += g_w[j];
    float C0 = 0.f;
#pragma unroll
    for (int c = 0; c < NBANDS; ++c) C0 -= mix_w[c] * la_b[c];
    const float cst = g_b[0] + Sg * C0;
    __syncthreads();
    const int t = T0 + tid;
    float v = cst;
#pragma unroll 1
    for (int c = 0; c < NBANDS; ++c) {
        float a = 0.f;
#pragma unroll
        for (int m = 0; m < 25; ++m) a = fmaf(H[c][m], sh[c][tid + 4 + m], a);
        v += a;
    }
    if (t < 7 || (t >= T_LEN - 7 && t < T_LEN)) {
        v = g_b[0];
        for (int jj = 0; jj < 15; ++jj) {
            int tp = t + jj - 7;
            if (tp < 0 || tp >= T_LEN) continue;
            float xm = C0;
            for (int c = 0; c < NBANDS; ++c) {
                float mw = mix_w[c];
                for (int k = 0; k < 11; ++k) {
                    int i = tp + k + 11 - T0;
                    xm = fmaf(mw * ((k == 5 ? 1.f : 0.f) - la_w[c * 11 + k]),
                              sh[c][i], xm);
                }
            }
            v = fmaf(g_w[jj], xm, v);
        }
    }
    float vmax = 0.f;
    if (t < T_LEN) {
        v = fmaxf(v, 0.f);
        xg[(size_t)b * T_LEN + t] = v;
        vmax = v;
    }
#pragma unroll
    for (int off = 32; off > 0; off >>= 1) vmax = fmaxf(vmax, __shfl_down(vmax, off));
    if ((tid & 63) == 0) red[tid >> 6] = vmax;
    __syncthreads();
    if (tid == 0) {
        float m = fmaxf(fmaxf(red[0], red[1]), fmaxf(red[2], red[3]));
        atomicMax(&m1_bits[b], __float_as_int(m));
    }
}

// ---------------- K3a: xg -> spectral_flux out + fa (sigmoid) + max(fa)
__global__ __launch_bounds__(256) void k3a(
        const float* __restrict__ xg, const int* __restrict__ m1_bits,
        const float* __restrict__ fc_w, const float* __restrict__ fc_b,
        const float* __restrict__ fg_w, const float* __restrict__ fg_b,
        float* __restrict__ sf_out, float* __restrict__ fa_out,
        int* __restrict__ m2_bits) {
    __shared__ float shfm[272];
    __shared__ float red[4];
    const int tid = threadIdx.x;
    const int t0 = blockIdx.x * 256;
    const int b = blockIdx.y;
    const float inv = 1.f / (__int_as_float(m1_bits[b]) + EPS);
    const float sfc = fc_w[0] + fc_w[1] + fc_w[2] + fc_w[3];
    const float fcb = fc_b[0];
    for (int i = tid; i < 270; i += 256) {
        int tt = t0 + i - 7;
        float v = 0.f;
        if (tt >= 0 && tt < T_LEN)
            v = fmaf(sfc, xg[(size_t)b * T_LEN + tt] * inv, fcb);
        shfm[i] = v;
    }
    __syncthreads();
    const int t = t0 + tid;
    float fs = fg_b[0];
#pragma unroll
    for (int k = 0; k < 15; ++k) fs = fmaf(fg_w[k], shfm[tid + k], fs);
    float sig = 1.f / (1.f + __expf(-fs));
    float v;
    if (t < T_LEN) {
        sf_out[(size_t)b * T_LEN + t] = xg[(size_t)b * T_LEN + t] * inv;
        fa_out[(size_t)b * T_LEN + t] = sig;
        v = sig;
    } else {
        v = 0.f;
    }
#pragma unroll
    for (int off = 32; off > 0; off >>= 1) v = fmaxf(v, __shfl_down(v, off));
    if ((tid & 63) == 0) red[tid >> 6] = v;
    __syncthreads();
    if (tid == 0) {
        float m = fmaxf(fmaxf(red[0], red[1]), fmaxf(red[2], red[3]));
        atomicMax(&m2_bits[b], __float_as_int(m));
    }
}

// ---------------- K3b: fused_nov = fa / (m2 + eps), in-place
__global__ void k3b(float* __restrict__ fa, const int* __restrict__ m2_bits) {
    int idx = blockIdx.x * 256 + threadIdx.x;
    if (idx >= BATCH * T_LEN) return;
    int b = idx / T_LEN;
    float inv = 1.f / (__int_as_float(m2_bits[b]) + EPS);
    fa[idx] = fa[idx] * inv;
}

extern "C" void kernel_launch(void* const* d_in, const int* in_sizes, int n_in,
                              void* d_out, int out_size, void* d_ws, size_t ws_size,
                              hipStream_t stream) {
    const float* x    = (const float*)d_in[0];
    const float* lg   = (const float*)d_in[1];
    const float* dw   = (const float*)d_in[2];
    const float* db   = (const float*)d_in[3];
    const float* law  = (const float*)d_in[4];
    const float* lab  = (const float*)d_in[5];
    const float* mixw = (const float*)d_in[6];
    const float* gw   = (const float*)d_in[7];
    const float* gb   = (const float*)d_in[8];
    const float* fcw  = (const float*)d_in[9];
    const float* fcb  = (const float*)d_in[10];
    const float* fgw  = (const float*)d_in[11];
    const float* fgb  = (const float*)d_in[12];

    float* ws = (float*)d_ws;
    float* xp = ws;                                   // 4*8*60000 floats
    float* xg = ws + (size_t)BATCH * NBANDS * T_LEN;  // 240,000 floats
    int*   m1 = (int*)(xg + (size_t)BATCH * T_LEN);   // m1[4] then m2[4]

    float* sf_out = (float*)d_out;
    float* fn_out = sf_out + (size_t)BATCH * T_LEN;

    const int tb256 = (T_LEN + 255) / 256;            // 235

    k1_xp<<<dim3(K1_NBX, NBANDS, BATCH), dim3(256), 0, stream>>>(
        x, lg, dw, db, xp, m1);
    k2_xg<<<dim3(tb256, BATCH), dim3(256), 0, stream>>>(
        xp, law, lab, mixw, gw, gb, xg, m1);
    k3a<<<dim3(tb256, BATCH), dim3(256), 0, stream>>>(
        xg, m1, fcw, fcb, fgw, fgb, sf_out, fn_out, m1 + 4);
    k3b<<<dim3((BATCH * T_LEN + 255) / 256), dim3(256), 0, stream>>>(fn_out, m1 + 4);
}

// Round 4
// 408.370 us; speedup vs baseline: 1.3680x; 1.0376x over previous
//
#include <hip/hip_runtime.h>
#include <cmath>

#define T_LEN 60000
#define BATCH 4
#define NBANDS 8
#define FB 32
#define EPS 1e-8f

#define K1_TILE 496
#define K1_ROWLEN 512   // staged floats per row: window [tile0-8, tile0+504)
#define K1_NBX ((T_LEN + K1_TILE - 1) / K1_TILE)   // 121

// ---------------- K1: x -> xp. grid (121, 8, 4), block 256.  (round-0 staged
// version — best measured: bulk-stage 32 rows x 512 floats of RAW x into LDS,
// one barrier, then log -> 5-tap diff -> relu -> f-sum from LDS.)
__global__ __launch_bounds__(256) void k1_xp(
        const float* __restrict__ x, const float* __restrict__ log_gamma,
        const float* __restrict__ diff_w, const float* __restrict__ diff_b,
        float* __restrict__ xp, int* __restrict__ mslots) {
    extern __shared__ float sh[];   // 32 * 512 floats = 64 KB
    const int tid = threadIdx.x;
    const int bx = blockIdx.x, band = blockIdx.y, b = blockIdx.z;
    if (bx == 0 && band == 0 && b == 0 && tid < 8)
        mslots[tid] = 0;  // zero m1[4], mG[4] (ws poisoned 0xAA)
    const int tile0 = bx * K1_TILE;
    const int w0 = tile0 - 8;  // global t of sh[r][0]
    const float* base = x + ((size_t)((b * NBANDS + band) * FB)) * T_LEN;
    const bool interior = (w0 >= 0) && (w0 + K1_ROWLEN <= T_LEN);
    if (interior) {
#pragma unroll
        for (int c = 0; c < 16; ++c) {
            const int idx = c * 1024 + tid * 4;   // float index into sh
            const int r = idx >> 9;               // row 0..31
            const int i = idx & 511;
            float4 v = *(const float4*)(base + (size_t)r * T_LEN + w0 + i);
            *(float4*)&sh[idx] = v;
        }
    } else {  // bx==0 or last: predicated scalar staging
        for (int c = 0; c < 16; ++c) {
            const int idx = c * 1024 + tid * 4;
            const int r = idx >> 9;
            const int i = idx & 511;
            const float* rowp = base + (size_t)r * T_LEN;
#pragma unroll
            for (int j = 0; j < 4; ++j) {
                const int t = w0 + i + j;
                sh[idx + j] = (t >= 0 && t < T_LEN) ? rowp[t] : 0.f;
            }
        }
    }
    __syncthreads();
    const float gamma = __expf(log_gamma[band]);
    float dw[5];
#pragma unroll
    for (int k = 0; k < 5; ++k) dw[k] = diff_w[band * 5 + k];
    const float db = diff_b[band];
    const int t0 = tile0 + 2 * tid;
    if (tid < 248 && t0 < T_LEN) {
        float acc0 = 0.f, acc1 = 0.f;
        const int i0 = 2 * tid + 6;  // sh row-index of t0-2 (8B-aligned)
#pragma unroll 4
        for (int r = 0; r < FB; ++r) {
            const float* rp = &sh[r * K1_ROWLEN];
            float2 pa = *(const float2*)(rp + i0);
            float2 pb = *(const float2*)(rp + i0 + 2);
            float2 pc = *(const float2*)(rp + i0 + 4);
            float e0 = __logf(fmaf(gamma, pa.x, 1.f));
            float e1 = __logf(fmaf(gamma, pa.y, 1.f));
            float e2 = __logf(fmaf(gamma, pb.x, 1.f));
            float e3 = __logf(fmaf(gamma, pb.y, 1.f));
            float e4 = __logf(fmaf(gamma, pc.x, 1.f));
            float e5 = __logf(fmaf(gamma, pc.y, 1.f));
            float xd0 = db, xd1 = db;
            xd0 = fmaf(dw[0], e0, xd0); xd1 = fmaf(dw[0], e1, xd1);
            xd0 = fmaf(dw[1], e1, xd0); xd1 = fmaf(dw[1], e2, xd1);
            xd0 = fmaf(dw[2], e2, xd0); xd1 = fmaf(dw[2], e3, xd1);
            xd0 = fmaf(dw[3], e3, xd0); xd1 = fmaf(dw[3], e4, xd1);
            xd0 = fmaf(dw[4], e4, xd0); xd1 = fmaf(dw[4], e5, xd1);
            acc0 += fmaxf(xd0, 0.f);
            acc1 += fmaxf(xd1, 0.f);
        }
        float* op = xp + ((size_t)(b * NBANDS + band)) * T_LEN + t0;
        op[0] = acc0;
        if (t0 + 1 < T_LEN) op[1] = acc1;
    }
}

// ---------------- K2: xp -> xg (composite 25-tap) PLUS G = 15-tap fg-conv of
// xg (computed from an extended xg tile in LDS), max(xg)->m1, max(interior G)
// ->mG, and the 14 boundary G values -> Gb. Enables a closed-form m2 in K3.
#define K2_STAGE 296  // xp staged [T0-20, T0+276)
#define XGE_N 270     // xg computed for [T0-7, T0+263)
__global__ __launch_bounds__(256) void k2_xg(
        const float* __restrict__ xp,
        const float* __restrict__ la_w, const float* __restrict__ la_b,
        const float* __restrict__ mix_w, const float* __restrict__ g_w,
        const float* __restrict__ g_b, const float* __restrict__ fg_w,
        float* __restrict__ xg, float* __restrict__ Gws,
        int* __restrict__ m1_bits, int* __restrict__ mG_bits,
        float* __restrict__ Gb) {
    __shared__ float sh[NBANDS][K2_STAGE];   // 9472 B
    __shared__ float H[NBANDS][25];
    __shared__ float xge[XGE_N];
    __shared__ float redV[4], redG[4];
    const int tid = threadIdx.x;
    const int T0 = blockIdx.x * 256;
    const int b = blockIdx.y;
    const float* xpb = xp + (size_t)b * NBANDS * T_LEN;
    // stage xp [T0-20, T0+276) for all 8 bands (zero-padded OOB)
    for (int idx = tid; idx < NBANDS * (K2_STAGE / 4); idx += 256) {
        int c = idx / (K2_STAGE / 4);
        int i4 = idx % (K2_STAGE / 4);
        int g = T0 - 20 + 4 * i4;
        const float* rowp = xpb + (size_t)c * T_LEN;
        float4 v;
        if (g >= 0 && g + 3 < T_LEN) {
            v = *(const float4*)(rowp + g);
        } else {
            v.x = (g + 0 >= 0 && g + 0 < T_LEN) ? rowp[g + 0] : 0.f;
            v.y = (g + 1 >= 0 && g + 1 < T_LEN) ? rowp[g + 1] : 0.f;
            v.z = (g + 2 >= 0 && g + 2 < T_LEN) ? rowp[g + 2] : 0.f;
            v.w = (g + 3 >= 0 && g + 3 < T_LEN) ? rowp[g + 3] : 0.f;
        }
        *(float4*)&sh[c][4 * i4] = v;
    }
    if (tid < 200) {
        int c = tid / 25, m = tid % 25;
        int klo = m - 14 > 0 ? m - 14 : 0;
        int khi = m < 10 ? m : 10;
        float mw = mix_w[c], s = 0.f;
        for (int k = klo; k <= khi; ++k)
            s += g_w[m - k] * (mw * ((k == 5 ? 1.f : 0.f) - la_w[c * 11 + k]));
        H[c][m] = s;
    }
    float Sg = 0.f;
#pragma unroll
    for (int j = 0; j < 15; ++j) Sg += g_w[j];
    float C0 = 0.f;
#pragma unroll
    for (int c = 0; c < NBANDS; ++c) C0 -= mix_w[c] * la_b[c];
    const float g_b0 = g_b[0];
    const float cst = g_b0 + Sg * C0;
    __syncthreads();

    auto compute_xg = [&](int p) -> float {
        const int t = T0 - 7 + p;
        if (t < 0 || t >= T_LEN) return 0.f;
        float v = cst;
#pragma unroll 1
        for (int c = 0; c < NBANDS; ++c) {
            float a = 0.f;
#pragma unroll
            for (int m = 0; m < 25; ++m) a = fmaf(H[c][m], sh[c][p + 1 + m], a);
            v += a;
        }
        if (t < 7 || t >= T_LEN - 7) {   // g-conv clips: exact two-stage redo
            v = g_b0;
            for (int jj = 0; jj < 15; ++jj) {
                int tp = t + jj - 7;
                if (tp < 0 || tp >= T_LEN) continue;
                float xm = C0;
                for (int c = 0; c < NBANDS; ++c) {
                    float mw = mix_w[c];
                    for (int k = 0; k < 11; ++k) {
                        int i = tp + k + 15 - T0;
                        xm = fmaf(mw * ((k == 5 ? 1.f : 0.f) - la_w[c * 11 + k]),
                                  sh[c][i], xm);
                    }
                }
                v = fmaf(g_w[jj], xm, v);
            }
        }
        return fmaxf(v, 0.f);
    };
    xge[tid] = compute_xg(tid);
    if (tid < XGE_N - 256) xge[256 + tid] = compute_xg(256 + tid);
    __syncthreads();

    const int t = T0 + tid;
    const float xv = xge[tid + 7];
    float G = 0.f;
#pragma unroll
    for (int k = 0; k < 15; ++k) G = fmaf(fg_w[k], xge[tid + k], G);
    float vmax = 0.f, gmax = 0.f;
    if (t < T_LEN) {
        xg[(size_t)b * T_LEN + t] = xv;
        Gws[(size_t)b * T_LEN + t] = G;
        vmax = xv;
        if (t >= 7 && t < T_LEN - 7) gmax = G;         // interior G
        else {                                          // 14 boundary G's
            int j = (t < 7) ? t : (t - (T_LEN - 7) + 7);
            Gb[b * 14 + j] = G;
        }
    }
#pragma unroll
    for (int off = 32; off > 0; off >>= 1) {
        vmax = fmaxf(vmax, __shfl_down(vmax, off));
        gmax = fmaxf(gmax, __shfl_down(gmax, off));
    }
    if ((tid & 63) == 0) { redV[tid >> 6] = vmax; redG[tid >> 6] = gmax; }
    __syncthreads();
    if (tid == 0) {
        float mv = fmaxf(fmaxf(redV[0], redV[1]), fmaxf(redV[2], redV[3]));
        float mg = fmaxf(fmaxf(redG[0], redG[1]), fmaxf(redG[2], redG[3]));
        atomicMax(&m1_bits[b], __float_as_int(mv));   // xg >= 0: bits trick ok
        atomicMax(&mG_bits[b], __float_as_int(mg));   // G >= 0 (gauss taps>0)
    }
}

// ---------------- K3: single barrier-free pass. m2 closed-form from mG +
// 14 boundary candidates (sigmoid monotone, s = sfc*inv >= 0). Writes both
// outputs; no fa round-trip, no atomics.
__global__ __launch_bounds__(256) void k3(
        const float* __restrict__ xg, const float* __restrict__ Gws,
        const int* __restrict__ m1_bits, const int* __restrict__ mG_bits,
        const float* __restrict__ Gb,
        const float* __restrict__ fc_w, const float* __restrict__ fc_b,
        const float* __restrict__ fg_w, const float* __restrict__ fg_b,
        float* __restrict__ sf_out, float* __restrict__ fn_out) {
    const int tid = threadIdx.x;
    const int t = blockIdx.x * 256 + tid;
    const int b = blockIdx.y;
    if (t >= T_LEN) return;
    const float inv = 1.f / (__int_as_float(m1_bits[b]) + EPS);
    const float sfc = fc_w[0] + fc_w[1] + fc_w[2] + fc_w[3];
    const float fcb = fc_b[0];
    const float fgb = fg_b[0];
    const float s = sfc * inv;
    float ps[15];   // ascending prefix sums of fg_w (all indices static)
    {
        float a = 0.f;
#pragma unroll
        for (int k = 0; k < 15; ++k) { a += fg_w[k]; ps[k] = a; }
    }
    const float Sfg = ps[14];
    const float C1i = fmaf(fcb, Sfg, fgb);
    float fsmax = fmaf(s, __int_as_float(mG_bits[b]), C1i);
#pragma unroll
    for (int j = 0; j < 7; ++j) {       // t = j: valid taps k in [7-j, 14]
        float W = Sfg - ps[6 - j];
        fsmax = fmaxf(fsmax, fmaf(s, Gb[b * 14 + j], fmaf(fcb, W, fgb)));
    }
#pragma unroll
    for (int j = 0; j < 7; ++j) {       // t = T-7+j: valid taps k in [0, 13-j]
        float W = ps[13 - j];
        fsmax = fmaxf(fsmax, fmaf(s, Gb[b * 14 + 7 + j], fmaf(fcb, W, fgb)));
    }
    const float m2 = 1.f / (1.f + __expf(-fsmax));
    const float inv2 = 1.f / (m2 + EPS);
    float W_own;
    if (t >= 7 && t < T_LEN - 7) {
        W_own = Sfg;
    } else {                            // 14 threads total per b
        W_own = 0.f;
        for (int k = 0; k < 15; ++k) {
            int tp = t - 7 + k;
            if (tp >= 0 && tp < T_LEN) W_own += fg_w[k];
        }
    }
    const float G = Gws[(size_t)b * T_LEN + t];
    const float fs = fmaf(s, G, fmaf(fcb, W_own, fgb));
    const float sig = 1.f / (1.f + __expf(-fs));
    const float xv = xg[(size_t)b * T_LEN + t];
    sf_out[(size_t)b * T_LEN + t] = xv * inv;
    fn_out[(size_t)b * T_LEN + t] = sig * inv2;
}

extern "C" void kernel_launch(void* const* d_in, const int* in_sizes, int n_in,
                              void* d_out, int out_size, void* d_ws, size_t ws_size,
                              hipStream_t stream) {
    const float* x    = (const float*)d_in[0];
    const float* lg   = (const float*)d_in[1];
    const float* dw   = (const float*)d_in[2];
    const float* db   = (const float*)d_in[3];
    const float* law  = (const float*)d_in[4];
    const float* lab  = (const float*)d_in[5];
    const float* mixw = (const float*)d_in[6];
    const float* gw   = (const float*)d_in[7];
    const float* gb   = (const float*)d_in[8];
    const float* fcw  = (const float*)d_in[9];
    const float* fcb  = (const float*)d_in[10];
    const float* fgw  = (const float*)d_in[11];
    const float* fgb  = (const float*)d_in[12];

    float* ws = (float*)d_ws;
    float* xp = ws;                                    // 1,920,000 floats
    float* xg = xp + (size_t)BATCH * NBANDS * T_LEN;   // 240,000 floats
    float* Gw = xg + (size_t)BATCH * T_LEN;            // 240,000 floats
    int*   m1 = (int*)(Gw + (size_t)BATCH * T_LEN);    // m1[4] then mG[4]
    int*   mG = m1 + 4;
    float* Gb = (float*)(mG + 4);                      // 56 floats

    float* sf_out = (float*)d_out;
    float* fn_out = sf_out + (size_t)BATCH * T_LEN;

    const int tb256 = (T_LEN + 255) / 256;             // 235

    k1_xp<<<dim3(K1_NBX, NBANDS, BATCH), dim3(256),
            FB * K1_ROWLEN * sizeof(float), stream>>>(
        x, lg, dw, db, xp, m1);
    k2_xg<<<dim3(tb256, BATCH), dim3(256), 0, stream>>>(
        xp, law, lab, mixw, gw, gb, fgw, xg, Gw, m1, mG, Gb);
    k3<<<dim3(tb256, BATCH), dim3(256), 0, stream>>>(
        xg, Gw, m1, mG, Gb, fcw, fcb, fgw, fgb, sf_out, fn_out);
}